// Round 6
// baseline (599.794 us; speedup 1.0000x reference)
//
#include <hip/hip_runtime.h>

#define N_NODES 100000
#define N_EDGES 1600000

typedef unsigned short ushort_t;
typedef __attribute__((ext_vector_type(8))) short bf16x8;
typedef __attribute__((ext_vector_type(4))) float f32x4;
typedef __attribute__((ext_vector_type(4))) int int4e;
typedef __attribute__((ext_vector_type(4))) unsigned short ushort4e;
typedef __attribute__((ext_vector_type(4))) float float4e;

__device__ __forceinline__ unsigned short f2bf(float f) {
  unsigned int u = __float_as_uint(f);
  u = (u + 0x7FFFu + ((u >> 16) & 1u)) >> 16;
  return (unsigned short)u;
}

// ---- degree accumulation + per-dst edge count ----
__global__ void k_deg_cnt(const int* __restrict__ ei, const float* __restrict__ ew,
                          float* __restrict__ deg, int* __restrict__ cnt) {
  int e = blockIdx.x * 256 + threadIdx.x;
  if (e >= N_EDGES) return;
  atomicAdd(&deg[ei[e]], ew[e]);
  atomicAdd(&cnt[ei[N_EDGES + e]], 1);
}

// ---- 2-level exclusive scan of cnt -> off ----
__global__ void k_scanA(const int* __restrict__ cnt, int* __restrict__ off,
                        int* __restrict__ bsum) {
  __shared__ int s[256];
  int t = threadIdx.x, i = blockIdx.x * 256 + t;
  int v = (i < N_NODES) ? cnt[i] : 0;
  s[t] = v;
  __syncthreads();
  for (int o = 1; o < 256; o <<= 1) {
    int add = (t >= o) ? s[t - o] : 0;
    __syncthreads();
    s[t] += add;
    __syncthreads();
  }
  off[i] = s[t] - v;                 // block-local exclusive
  if (t == 255) bsum[blockIdx.x] = s[255];
}

__global__ void k_scanB(int* __restrict__ bsum, int* __restrict__ boff) {
  __shared__ int s[512];
  int t = threadIdx.x;
  int v = (t < 391) ? bsum[t] : 0;
  s[t] = v;
  __syncthreads();
  for (int o = 1; o < 512; o <<= 1) {
    int add = (t >= o) ? s[t - o] : 0;
    __syncthreads();
    s[t] += add;
    __syncthreads();
  }
  if (t < 391) boff[t] = s[t] - v;   // exclusive block offsets
}

__global__ void k_scanC(int* __restrict__ off, const int* __restrict__ boff) {
  int i = blockIdx.x * 256 + threadIdx.x;
  off[i] += boff[blockIdx.x];
}

// ---- compact CSR scatter: bE[off[c] + fill[c]++] = (row, w) ----
__global__ void k_bucket(const int* __restrict__ ei, const float* __restrict__ ew,
                         const float* __restrict__ deg, const int* __restrict__ off,
                         int* __restrict__ fill, int2* __restrict__ bE) {
  int e = blockIdx.x * 256 + threadIdx.x;
  if (e >= N_EDGES) return;
  int r = ei[e], c = ei[N_EDGES + e];
  float dr = deg[r], dc = deg[c];
  float ir = dr > 0.f ? rsqrtf(dr) : 0.f;
  float ic = dc > 0.f ? rsqrtf(dc) : 0.f;
  float wv = -ir * ew[e] * ic;
  int pos = off[c] + atomicAdd(&fill[c], 1);
  bE[pos] = make_int2(r, __float_as_int(wv));
}

// ---- pack X (cols 0-127) and H (cols 128-255) into bf16 A-matrix U [N][512] ----
__global__ void k_pack_xh(const float* __restrict__ X, const float* __restrict__ H,
                          ushort_t* __restrict__ U) {
  int i = blockIdx.x * 256 + threadIdx.x;
  if (i >= N_NODES * 32) return;
  int n = i >> 5, q = i & 31;
  float4 x = *(const float4*)(X + (size_t)n * 128 + q * 4);
  float4 h = *(const float4*)(H + (size_t)n * 128 + q * 4);
  ushort4 a, bb;
  a.x = f2bf(x.x); a.y = f2bf(x.y); a.z = f2bf(x.z); a.w = f2bf(x.w);
  bb.x = f2bf(h.x); bb.y = f2bf(h.y); bb.z = f2bf(h.z); bb.w = f2bf(h.w);
  *(ushort4*)(U + (size_t)n * 512 + q * 4) = a;
  *(ushort4*)(U + (size_t)n * 512 + 128 + q * 4) = bb;
}

#define FMA4(A, W, V) \
  A.x = fmaf(W, V.x, A.x); A.y = fmaf(W, V.y, A.y); \
  A.z = fmaf(W, V.z, A.z); A.w = fmaf(W, V.w, A.w);

// ---- ILP gather: 32 lanes/node, 16 nodes/block (512 thr), CSR meta ----
template <int PHASE>
__global__ __launch_bounds__(512) void k_gather(
    const int* __restrict__ cnt, const int* __restrict__ off,
    const int2* __restrict__ bE, const float* __restrict__ src,
    const float* __restrict__ H, float* __restrict__ T1,
    ushort_t* __restrict__ U) {
  int g = threadIdx.x >> 5, lane = threadIdx.x & 31;
  int node = blockIdx.x * 16 + g;
  if (node >= N_NODES) return;
  int cn = cnt[node];
  const int2* be = bE + off[node];
  const float4* s4 = (const float4*)src;

  float4 z = {0.f, 0.f, 0.f, 0.f};
  float4 a0 = z, a1 = z, a2 = z, a3 = z, a4 = z, a5 = z, a6 = z, a7 = z;
  int i = 0;
  for (; i + 8 <= cn; i += 8) {
    int4e p0 = __builtin_nontemporal_load((const int4e*)(be + i));
    int4e p1 = __builtin_nontemporal_load((const int4e*)(be + i + 2));
    int4e p2 = __builtin_nontemporal_load((const int4e*)(be + i + 4));
    int4e p3 = __builtin_nontemporal_load((const int4e*)(be + i + 6));
    float4 v0 = s4[(size_t)p0.x * 32 + lane];
    float4 v1 = s4[(size_t)p0.z * 32 + lane];
    float4 v2 = s4[(size_t)p1.x * 32 + lane];
    float4 v3 = s4[(size_t)p1.z * 32 + lane];
    float4 v4 = s4[(size_t)p2.x * 32 + lane];
    float4 v5 = s4[(size_t)p2.z * 32 + lane];
    float4 v6 = s4[(size_t)p3.x * 32 + lane];
    float4 v7 = s4[(size_t)p3.z * 32 + lane];
    FMA4(a0, __int_as_float(p0.y), v0); FMA4(a1, __int_as_float(p0.w), v1);
    FMA4(a2, __int_as_float(p1.y), v2); FMA4(a3, __int_as_float(p1.w), v3);
    FMA4(a4, __int_as_float(p2.y), v4); FMA4(a5, __int_as_float(p2.w), v5);
    FMA4(a6, __int_as_float(p3.y), v6); FMA4(a7, __int_as_float(p3.w), v7);
  }
  for (; i + 4 <= cn; i += 4) {
    int4e p0 = __builtin_nontemporal_load((const int4e*)(be + i));
    int4e p1 = __builtin_nontemporal_load((const int4e*)(be + i + 2));
    float4 v0 = s4[(size_t)p0.x * 32 + lane];
    float4 v1 = s4[(size_t)p0.z * 32 + lane];
    float4 v2 = s4[(size_t)p1.x * 32 + lane];
    float4 v3 = s4[(size_t)p1.z * 32 + lane];
    FMA4(a0, __int_as_float(p0.y), v0); FMA4(a1, __int_as_float(p0.w), v1);
    FMA4(a2, __int_as_float(p1.y), v2); FMA4(a3, __int_as_float(p1.w), v3);
  }
  for (; i < cn; ++i) {
    int2 p = be[i];
    float4 v = s4[(size_t)p.x * 32 + lane];
    FMA4(a0, __int_as_float(p.y), v);
  }
  float4 acc;
  acc.x = ((a0.x + a1.x) + (a2.x + a3.x)) + ((a4.x + a5.x) + (a6.x + a7.x));
  acc.y = ((a0.y + a1.y) + (a2.y + a3.y)) + ((a4.y + a5.y) + (a6.y + a7.y));
  acc.z = ((a0.z + a1.z) + (a2.z + a3.z)) + ((a4.z + a5.z) + (a6.z + a7.z));
  acc.w = ((a0.w + a1.w) + (a2.w + a3.w)) + ((a4.w + a5.w) + (a6.w + a7.w));

  if (PHASE == 1) {
    float4e af = {acc.x, acc.y, acc.z, acc.w};
    __builtin_nontemporal_store(af, (float4e*)(T1 + (size_t)node * 128 + lane * 4));
    ushort4e u = {f2bf(acc.x), f2bf(acc.y), f2bf(acc.z), f2bf(acc.w)};
    __builtin_nontemporal_store(u, (ushort4e*)(U + (size_t)node * 512 + 256 + lane * 4));
  } else {
    float4 h = *(const float4*)(H + (size_t)node * 128 + lane * 4);
    ushort4e u = {f2bf(2.f * acc.x - h.x), f2bf(2.f * acc.y - h.y),
                  f2bf(2.f * acc.z - h.z), f2bf(2.f * acc.w - h.w)};
    __builtin_nontemporal_store(u, (ushort4e*)(U + (size_t)node * 512 + 384 + lane * 4));
  }
}

// ---- build B^T [512 j][512 k] bf16, col interleave j = d*4 + g; plus bias[512] ----
__global__ void k_bt(const float* __restrict__ W, const float* __restrict__ b,
                     const float* __restrict__ cW, const float* __restrict__ cb,
                     ushort_t* __restrict__ Bt, float* __restrict__ bias) {
  int idx = blockIdx.x * 256 + threadIdx.x;
  if (idx >= 512 * 512) return;
  int j = idx >> 9, k = idx & 511;
  int dd = j >> 2, g = j & 3;
  float v;
  if (k < 128) v = W[(g * 128 + k) * 128 + dd];
  else {
    int kk = k - 128;
    int blk = kk >> 7;
    v = cW[((g * 3 + blk) * 128 + (kk & 127)) * 128 + dd];
  }
  Bt[idx] = f2bf(v);
  if (k == 0) bias[j] = b[g * 128 + dd] + cb[g * 128 + dd];
}

// ---- fused GEMM, counted-vmcnt depth-2 pipeline + per-ks interleave + setprio ----
__global__ __launch_bounds__(256) void k_gemm(
    const ushort_t* __restrict__ U, const ushort_t* __restrict__ Bt,
    const float* __restrict__ bias, const float* __restrict__ C,
    float* __restrict__ out) {
  __shared__ char ldsRaw[65536];     // 2 x (16K A + 16K B); epilogue reuses as f32 tile
  char* ldsA0 = ldsRaw;
  char* ldsB0 = ldsRaw + 16384;
  char* ldsA1 = ldsRaw + 32768;
  char* ldsB1 = ldsRaw + 49152;
  float* ldsF = (float*)ldsRaw;

  const int tid = threadIdx.x;
  const int lane = tid & 63;
  const int w = tid >> 6;
  const int wr = w >> 1, wc = w & 1;
  // XCD-bijective swizzle: 3128 = 8*391; 4 n-tiles of an m-panel stay in one XCD
  const int b = blockIdx.x;
  const int g = (b & 7) * 391 + (b >> 3);
  const int m0 = (g >> 2) * 128;
  const int n0 = (g & 3) * 128;
  const int l15 = lane & 15;
  const int l4 = lane >> 4;

  auto stage_half = [&](int kt, char* la_base, char* lb_base, int h) {
    const int k0 = kt * 64;
#pragma unroll
    for (int is = 2 * h; is < 2 * h + 2; ++is) {
      int s = is * 256 + tid;
      int row = s >> 3;
      int cs = (s & 7) ^ (row & 7);        // inverse-swizzled global source chunk
      const ushort_t* ga = U + (size_t)(m0 + row) * 512 + k0 + cs * 8;
      const ushort_t* gb = Bt + (size_t)(n0 + row) * 512 + k0 + cs * 8;
      char* la = la_base + (is * 256 + (tid & 192)) * 16;   // wave-uniform base
      char* lb = lb_base + (is * 256 + (tid & 192)) * 16;
      __builtin_amdgcn_global_load_lds((const __attribute__((address_space(1))) void*)ga,
                                       (__attribute__((address_space(3))) void*)la, 16, 0, 0);
      __builtin_amdgcn_global_load_lds((const __attribute__((address_space(1))) void*)gb,
                                       (__attribute__((address_space(3))) void*)lb, 16, 0, 0);
    }
  };

  // C prefetch (epilogue operand), coalesced, issued before staging
  const int fcol = tid & 31;
  const int rbase = tid >> 5;
  float cpre[16];
#pragma unroll
  for (int half = 0; half < 2; ++half)
#pragma unroll
    for (int k = 0; k < 8; ++k) {
      int n = m0 + half * 64 + rbase + k * 8;
      int dg = (n0 >> 2) + fcol;
      cpre[half * 8 + k] = (n < N_NODES) ? C[(size_t)n * 128 + dg] : 0.f;
    }

  // loop-invariant swizzled LDS read offsets (slot independent of mi: 16%8==0)
  int offA[2][4], offB[2][4];
#pragma unroll
  for (int ks = 0; ks < 2; ++ks) {
    int slot = ((ks * 4 + l4) ^ (l15 & 7)) * 16;
#pragma unroll
    for (int i = 0; i < 4; ++i) {
      offA[ks][i] = (wr * 64 + i * 16 + l15) * 128 + slot;
      offB[ks][i] = (wc * 64 + i * 16 + l15) * 128 + slot;
    }
  }

  f32x4 acc[4][4] = {};

  stage_half(0, ldsA0, ldsB0, 0);
  stage_half(0, ldsA0, ldsB0, 1);          // 8 loads outstanding

  for (int kt = 0; kt < 8; ++kt) {
    char* curA = (kt & 1) ? ldsA1 : ldsA0;
    char* curB = (kt & 1) ? ldsB1 : ldsB0;
    char* nA = (kt & 1) ? ldsA0 : ldsA1;
    char* nB = (kt & 1) ? ldsB0 : ldsB1;
    if (kt < 7) {
      stage_half(kt + 1, nA, nB, 0);       // 4 loads -> 12 outstanding
      asm volatile("s_waitcnt vmcnt(4)" ::: "memory");  // stage(kt) landed; half1 in flight
    } else {
      asm volatile("s_waitcnt vmcnt(0)" ::: "memory");
    }
    __builtin_amdgcn_s_barrier();          // A: cur fully staged for all threads
    __builtin_amdgcn_sched_barrier(0);

    // ---- sub-phase ks=0 ----
    {
      bf16x8 af[4], bfr[4];
#pragma unroll
      for (int mi = 0; mi < 4; ++mi) af[mi] = *(const bf16x8*)(curA + offA[0][mi]);
#pragma unroll
      for (int ni = 0; ni < 4; ++ni) bfr[ni] = *(const bf16x8*)(curB + offB[0][ni]);
      asm volatile("s_waitcnt lgkmcnt(0)" ::: "memory");
      __builtin_amdgcn_sched_barrier(0);
      __builtin_amdgcn_s_setprio(1);
#pragma unroll
      for (int mi = 0; mi < 4; ++mi)
#pragma unroll
        for (int ni = 0; ni < 4; ++ni)
          acc[mi][ni] = __builtin_amdgcn_mfma_f32_16x16x32_bf16(af[mi], bfr[ni], acc[mi][ni], 0, 0, 0);
      __builtin_amdgcn_s_setprio(0);
    }
    if (kt < 7) stage_half(kt + 1, nA, nB, 1);  // 4 loads -> 8 outstanding
    // ---- sub-phase ks=1 ----
    {
      bf16x8 af[4], bfr[4];
#pragma unroll
      for (int mi = 0; mi < 4; ++mi) af[mi] = *(const bf16x8*)(curA + offA[1][mi]);
#pragma unroll
      for (int ni = 0; ni < 4; ++ni) bfr[ni] = *(const bf16x8*)(curB + offB[1][ni]);
      asm volatile("s_waitcnt lgkmcnt(0)" ::: "memory");
      __builtin_amdgcn_sched_barrier(0);
      __builtin_amdgcn_s_setprio(1);
#pragma unroll
      for (int mi = 0; mi < 4; ++mi)
#pragma unroll
        for (int ni = 0; ni < 4; ++ni)
          acc[mi][ni] = __builtin_amdgcn_mfma_f32_16x16x32_bf16(af[mi], bfr[ni], acc[mi][ni], 0, 0, 0);
      __builtin_amdgcn_s_setprio(0);
    }
    __builtin_amdgcn_s_barrier();          // B: all done reading cur; safe to overwrite
  }

  // epilogue: two row-halves through LDS, then fused LSTM elementwise
#pragma unroll
  for (int half = 0; half < 2; ++half) {
    if (wr == half) {
#pragma unroll
      for (int ni = 0; ni < 4; ++ni) {
        int col = wc * 64 + ni * 16 + l15;
        float bv = bias[n0 + col];
#pragma unroll
        for (int mi = 0; mi < 4; ++mi)
#pragma unroll
          for (int r = 0; r < 4; ++r)
            ldsF[(mi * 16 + l4 * 4 + r) * 132 + col] = acc[mi][ni][r] + bv;
      }
    }
    __syncthreads();
#pragma unroll
    for (int k = 0; k < 8; ++k) {
      int p = tid + k * 256;
      int rl = p >> 5, f = p & 31;
      int n = m0 + half * 64 + rl;
      if (n < N_NODES) {
        float4 pre = *(const float4*)&ldsF[rl * 132 + f * 4];
        int dg = (n0 >> 2) + f;
        float ig = __builtin_amdgcn_rcpf(1.f + __expf(-pre.x));
        float fg = __builtin_amdgcn_rcpf(1.f + __expf(-pre.y));
        float ec = __expf(-2.f * fabsf(pre.z));
        float tg = __builtin_copysignf((1.f - ec) * __builtin_amdgcn_rcpf(1.f + ec), pre.z);
        float og = __builtin_amdgcn_rcpf(1.f + __expf(-pre.w));
        float cOld = cpre[half * 8 + k];
        float cn = fg * cOld + ig * tg;
        float en = __expf(-2.f * fabsf(cn));
        float th = __builtin_copysignf((1.f - en) * __builtin_amdgcn_rcpf(1.f + en), cn);
        out[(size_t)n * 128 + dg] = og * th;
      }
    }
    __syncthreads();
  }
}

extern "C" void kernel_launch(void* const* d_in, const int* in_sizes, int n_in,
                              void* d_out, int out_size, void* d_ws, size_t ws_size,
                              hipStream_t stream) {
  const float* X  = (const float*)d_in[0];
  const int*   ei = (const int*)d_in[1];
  const float* ew = (const float*)d_in[2];
  const float* H  = (const float*)d_in[3];
  const float* C  = (const float*)d_in[4];
  const float* W  = (const float*)d_in[5];
  const float* b  = (const float*)d_in[6];
  const float* cW = (const float*)d_in[7];
  const float* cb = (const float*)d_in[8];
  float* out = (float*)d_out;
  char* ws = (char*)d_ws;

  float*    deg  = (float*)(ws);                 // 0.5 MB
  int*      cnt  = (int*)(ws + 0x80000);         // 0.5 MB
  int*      fill = (int*)(ws + 0x100000);        // 0.5 MB
  int*      off  = (int*)(ws + 0x180000);        // 0.5 MB (100096 ints)
  int*      bsum = (int*)(ws + 0x200000);        // block sums (391)
  int*      boff = (int*)(ws + 0x202000);
  int2*     bE   = (int2*)(ws + 0x300000);       // 12.8 MB compact CSR (row, w)
  float*    T1   = (float*)(ws + 0x1000000);     // 51.2 MB
  ushort_t* U    = (ushort_t*)(ws + 0x4200000);  // 100096 x 512 bf16 = 102.5 MB
  ushort_t* Bt   = (ushort_t*)(ws + 0xA400000);  // 512 KB
  float*    bias = (float*)(ws + 0xA480000);     // 2 KB

  hipMemsetAsync(ws, 0, 0x180000, stream);       // zero deg + cnt + fill

  k_deg_cnt<<<(N_EDGES + 255) / 256, 256, 0, stream>>>(ei, ew, deg, cnt);
  k_scanA<<<391, 256, 0, stream>>>(cnt, off, bsum);
  k_scanB<<<1, 512, 0, stream>>>(bsum, boff);
  k_scanC<<<391, 256, 0, stream>>>(off, boff);
  k_bucket<<<(N_EDGES + 255) / 256, 256, 0, stream>>>(ei, ew, deg, off, fill, bE);
  k_pack_xh<<<(N_NODES * 32 + 255) / 256, 256, 0, stream>>>(X, H, U);
  k_bt<<<1024, 256, 0, stream>>>(W, b, cW, cb, Bt, bias);
  k_gather<1><<<(N_NODES + 15) / 16, 512, 0, stream>>>(cnt, off, bE, H, nullptr, T1, U);
  k_gather<2><<<(N_NODES + 15) / 16, 512, 0, stream>>>(cnt, off, bE, T1, H, nullptr, U);
  k_gemm<<<3128, 256, 0, stream>>>(U, Bt, bias, C, out);
}

// Round 7
// 540.881 us; speedup vs baseline: 1.1089x; 1.1089x over previous
//
#include <hip/hip_runtime.h>

#define N_NODES 100000
#define N_EDGES 1600000
#define CAP 64

typedef unsigned short ushort_t;
typedef __attribute__((ext_vector_type(8))) short bf16x8;
typedef __attribute__((ext_vector_type(4))) float f32x4;
typedef __attribute__((ext_vector_type(4))) int int4e;
typedef __attribute__((ext_vector_type(4))) unsigned short ushort4e;
typedef __attribute__((ext_vector_type(4))) float float4e;

__device__ __forceinline__ unsigned short f2bf(float f) {
  unsigned int u = __float_as_uint(f);
  u = (u + 0x7FFFu + ((u >> 16) & 1u)) >> 16;
  return (unsigned short)u;
}

// ---- fused: deg atomics (blocks 0-6249) | pack X,H->U bf16 (6250-18749) | B^T+bias (18750-19773) ----
__global__ __launch_bounds__(256) void k_misc(
    const int* __restrict__ ei, const float* __restrict__ ew,
    const float* __restrict__ X, const float* __restrict__ H,
    float* __restrict__ deg, ushort_t* __restrict__ U,
    const float* __restrict__ W, const float* __restrict__ b,
    const float* __restrict__ cW, const float* __restrict__ cb,
    ushort_t* __restrict__ Bt, float* __restrict__ bias) {
  int bid = blockIdx.x;
  if (bid < 6250) {                       // deg[row] += ew  (atomic-latency-bound)
    int e = bid * 256 + threadIdx.x;
    atomicAdd(&deg[ei[e]], ew[e]);
  } else if (bid < 18750) {               // pack X (cols 0-127), H (cols 128-255)
    int i = (bid - 6250) * 256 + threadIdx.x;
    int n = i >> 5, q = i & 31;
    float4 x = *(const float4*)(X + (size_t)n * 128 + q * 4);
    float4 h = *(const float4*)(H + (size_t)n * 128 + q * 4);
    ushort4 a, bb;
    a.x = f2bf(x.x); a.y = f2bf(x.y); a.z = f2bf(x.z); a.w = f2bf(x.w);
    bb.x = f2bf(h.x); bb.y = f2bf(h.y); bb.z = f2bf(h.z); bb.w = f2bf(h.w);
    *(ushort4*)(U + (size_t)n * 512 + q * 4) = a;
    *(ushort4*)(U + (size_t)n * 512 + 128 + q * 4) = bb;
  } else {                                // B^T [512 j][512 k], j = d*4+g; bias
    int idx = (bid - 18750) * 256 + threadIdx.x;
    int j = idx >> 9, k = idx & 511;
    int dd = j >> 2, g = j & 3;
    float v;
    if (k < 128) v = W[(g * 128 + k) * 128 + dd];
    else {
      int kk = k - 128;
      int blk = kk >> 7;
      v = cW[((g * 3 + blk) * 128 + (kk & 127)) * 128 + dd];
    }
    Bt[idx] = f2bf(v);
    if (k == 0) bias[j] = b[g * 128 + dd] + cb[g * 128 + dd];
  }
}

// ---- bucket edges by dst, storing (row, rsqrt(deg[row])*ew); dinv[c] applied in gather ----
__global__ void k_bucket(const int* __restrict__ ei, const float* __restrict__ ew,
                         const float* __restrict__ deg, int* __restrict__ cnt,
                         int2* __restrict__ bE) {
  int e = blockIdx.x * 256 + threadIdx.x;
  if (e >= N_EDGES) return;
  int r = ei[e], c = ei[N_EDGES + e];
  float dr = deg[r];
  float s = dr > 0.f ? rsqrtf(dr) * ew[e] : 0.f;
  int pos = atomicAdd(&cnt[c], 1);
  if (pos < CAP) bE[c * CAP + pos] = make_int2(r, __float_as_int(s));
}

#define FMA4(A, W, V) \
  A.x = fmaf(W, V.x, A.x); A.y = fmaf(W, V.y, A.y); \
  A.z = fmaf(W, V.z, A.z); A.w = fmaf(W, V.w, A.w);

// ---- ILP gather: 32 lanes/node, 16 nodes/block (512 thr); result scaled by -rsqrt(deg[c]) ----
template <int PHASE>
__global__ __launch_bounds__(512) void k_gather(
    const int* __restrict__ cnt, const int2* __restrict__ bE,
    const float* __restrict__ deg, const float* __restrict__ src,
    const float* __restrict__ H, float* __restrict__ T1,
    ushort_t* __restrict__ U) {
  int g = threadIdx.x >> 5, lane = threadIdx.x & 31;
  int node = blockIdx.x * 16 + g;
  if (node >= N_NODES) return;
  int cn = cnt[node]; if (cn > CAP) cn = CAP;
  const int2* be = bE + node * CAP;
  const float4* s4 = (const float4*)src;
  float dc = deg[node];
  float sc = dc > 0.f ? -rsqrtf(dc) : 0.f;   // -dinv[c], factored out of the sum

  float4 z = {0.f, 0.f, 0.f, 0.f};
  float4 a0 = z, a1 = z, a2 = z, a3 = z, a4 = z, a5 = z, a6 = z, a7 = z;
  int i = 0;
  for (; i + 8 <= cn; i += 8) {
    int4e p0 = __builtin_nontemporal_load((const int4e*)(be + i));
    int4e p1 = __builtin_nontemporal_load((const int4e*)(be + i + 2));
    int4e p2 = __builtin_nontemporal_load((const int4e*)(be + i + 4));
    int4e p3 = __builtin_nontemporal_load((const int4e*)(be + i + 6));
    float4 v0 = s4[(size_t)p0.x * 32 + lane];
    float4 v1 = s4[(size_t)p0.z * 32 + lane];
    float4 v2 = s4[(size_t)p1.x * 32 + lane];
    float4 v3 = s4[(size_t)p1.z * 32 + lane];
    float4 v4 = s4[(size_t)p2.x * 32 + lane];
    float4 v5 = s4[(size_t)p2.z * 32 + lane];
    float4 v6 = s4[(size_t)p3.x * 32 + lane];
    float4 v7 = s4[(size_t)p3.z * 32 + lane];
    FMA4(a0, __int_as_float(p0.y), v0); FMA4(a1, __int_as_float(p0.w), v1);
    FMA4(a2, __int_as_float(p1.y), v2); FMA4(a3, __int_as_float(p1.w), v3);
    FMA4(a4, __int_as_float(p2.y), v4); FMA4(a5, __int_as_float(p2.w), v5);
    FMA4(a6, __int_as_float(p3.y), v6); FMA4(a7, __int_as_float(p3.w), v7);
  }
  for (; i + 4 <= cn; i += 4) {
    int4e p0 = __builtin_nontemporal_load((const int4e*)(be + i));
    int4e p1 = __builtin_nontemporal_load((const int4e*)(be + i + 2));
    float4 v0 = s4[(size_t)p0.x * 32 + lane];
    float4 v1 = s4[(size_t)p0.z * 32 + lane];
    float4 v2 = s4[(size_t)p1.x * 32 + lane];
    float4 v3 = s4[(size_t)p1.z * 32 + lane];
    FMA4(a0, __int_as_float(p0.y), v0); FMA4(a1, __int_as_float(p0.w), v1);
    FMA4(a2, __int_as_float(p1.y), v2); FMA4(a3, __int_as_float(p1.w), v3);
  }
  for (; i < cn; ++i) {
    int2 p = be[i];
    float4 v = s4[(size_t)p.x * 32 + lane];
    FMA4(a0, __int_as_float(p.y), v);
  }
  float4 acc;
  acc.x = sc * (((a0.x + a1.x) + (a2.x + a3.x)) + ((a4.x + a5.x) + (a6.x + a7.x)));
  acc.y = sc * (((a0.y + a1.y) + (a2.y + a3.y)) + ((a4.y + a5.y) + (a6.y + a7.y)));
  acc.z = sc * (((a0.z + a1.z) + (a2.z + a3.z)) + ((a4.z + a5.z) + (a6.z + a7.z)));
  acc.w = sc * (((a0.w + a1.w) + (a2.w + a3.w)) + ((a4.w + a5.w) + (a6.w + a7.w)));

  if (PHASE == 1) {
    float4e af = {acc.x, acc.y, acc.z, acc.w};
    __builtin_nontemporal_store(af, (float4e*)(T1 + (size_t)node * 128 + lane * 4));
    ushort4e u = {f2bf(acc.x), f2bf(acc.y), f2bf(acc.z), f2bf(acc.w)};
    __builtin_nontemporal_store(u, (ushort4e*)(U + (size_t)node * 512 + 256 + lane * 4));
  } else {
    float4 h = *(const float4*)(H + (size_t)node * 128 + lane * 4);
    ushort4e u = {f2bf(2.f * acc.x - h.x), f2bf(2.f * acc.y - h.y),
                  f2bf(2.f * acc.z - h.z), f2bf(2.f * acc.w - h.w)};
    __builtin_nontemporal_store(u, (ushort4e*)(U + (size_t)node * 512 + 384 + lane * 4));
  }
}

// ---- fused GEMM, counted-vmcnt depth-2 pipeline + per-ks interleave + setprio ----
__global__ __launch_bounds__(256) void k_gemm(
    const ushort_t* __restrict__ U, const ushort_t* __restrict__ Bt,
    const float* __restrict__ bias, const float* __restrict__ C,
    float* __restrict__ out) {
  __shared__ char ldsRaw[65536];     // 2 x (16K A + 16K B); epilogue reuses as f32 tile
  char* ldsA0 = ldsRaw;
  char* ldsB0 = ldsRaw + 16384;
  char* ldsA1 = ldsRaw + 32768;
  char* ldsB1 = ldsRaw + 49152;
  float* ldsF = (float*)ldsRaw;

  const int tid = threadIdx.x;
  const int lane = tid & 63;
  const int w = tid >> 6;
  const int wr = w >> 1, wc = w & 1;
  // XCD-bijective swizzle: 3128 = 8*391; 4 n-tiles of an m-panel stay in one XCD
  const int b = blockIdx.x;
  const int g = (b & 7) * 391 + (b >> 3);
  const int m0 = (g >> 2) * 128;
  const int n0 = (g & 3) * 128;
  const int l15 = lane & 15;
  const int l4 = lane >> 4;

  auto stage_half = [&](int kt, char* la_base, char* lb_base, int h) {
    const int k0 = kt * 64;
#pragma unroll
    for (int is = 2 * h; is < 2 * h + 2; ++is) {
      int s = is * 256 + tid;
      int row = s >> 3;
      int cs = (s & 7) ^ (row & 7);        // inverse-swizzled global source chunk
      const ushort_t* ga = U + (size_t)(m0 + row) * 512 + k0 + cs * 8;
      const ushort_t* gb = Bt + (size_t)(n0 + row) * 512 + k0 + cs * 8;
      char* la = la_base + (is * 256 + (tid & 192)) * 16;   // wave-uniform base
      char* lb = lb_base + (is * 256 + (tid & 192)) * 16;
      __builtin_amdgcn_global_load_lds((const __attribute__((address_space(1))) void*)ga,
                                       (__attribute__((address_space(3))) void*)la, 16, 0, 0);
      __builtin_amdgcn_global_load_lds((const __attribute__((address_space(1))) void*)gb,
                                       (__attribute__((address_space(3))) void*)lb, 16, 0, 0);
    }
  };

  // C prefetch (epilogue operand), coalesced, issued before staging
  const int fcol = tid & 31;
  const int rbase = tid >> 5;
  float cpre[16];
#pragma unroll
  for (int half = 0; half < 2; ++half)
#pragma unroll
    for (int k = 0; k < 8; ++k) {
      int n = m0 + half * 64 + rbase + k * 8;
      int dg = (n0 >> 2) + fcol;
      cpre[half * 8 + k] = (n < N_NODES) ? C[(size_t)n * 128 + dg] : 0.f;
    }

  // loop-invariant swizzled LDS read offsets (slot independent of mi: 16%8==0)
  int offA[2][4], offB[2][4];
#pragma unroll
  for (int ks = 0; ks < 2; ++ks) {
    int slot = ((ks * 4 + l4) ^ (l15 & 7)) * 16;
#pragma unroll
    for (int i = 0; i < 4; ++i) {
      offA[ks][i] = (wr * 64 + i * 16 + l15) * 128 + slot;
      offB[ks][i] = (wc * 64 + i * 16 + l15) * 128 + slot;
    }
  }

  f32x4 acc[4][4] = {};

  stage_half(0, ldsA0, ldsB0, 0);
  stage_half(0, ldsA0, ldsB0, 1);          // 8 loads outstanding

  for (int kt = 0; kt < 8; ++kt) {
    char* curA = (kt & 1) ? ldsA1 : ldsA0;
    char* curB = (kt & 1) ? ldsB1 : ldsB0;
    char* nA = (kt & 1) ? ldsA0 : ldsA1;
    char* nB = (kt & 1) ? ldsB0 : ldsB1;
    if (kt < 7) {
      stage_half(kt + 1, nA, nB, 0);       // 4 loads -> 12 outstanding
      asm volatile("s_waitcnt vmcnt(4)" ::: "memory");  // stage(kt) landed; half1 in flight
    } else {
      asm volatile("s_waitcnt vmcnt(0)" ::: "memory");
    }
    __builtin_amdgcn_s_barrier();          // A: cur fully staged for all threads
    __builtin_amdgcn_sched_barrier(0);

    // ---- sub-phase ks=0 ----
    {
      bf16x8 af[4], bfr[4];
#pragma unroll
      for (int mi = 0; mi < 4; ++mi) af[mi] = *(const bf16x8*)(curA + offA[0][mi]);
#pragma unroll
      for (int ni = 0; ni < 4; ++ni) bfr[ni] = *(const bf16x8*)(curB + offB[0][ni]);
      asm volatile("s_waitcnt lgkmcnt(0)" ::: "memory");
      __builtin_amdgcn_sched_barrier(0);
      __builtin_amdgcn_s_setprio(1);
#pragma unroll
      for (int mi = 0; mi < 4; ++mi)
#pragma unroll
        for (int ni = 0; ni < 4; ++ni)
          acc[mi][ni] = __builtin_amdgcn_mfma_f32_16x16x32_bf16(af[mi], bfr[ni], acc[mi][ni], 0, 0, 0);
      __builtin_amdgcn_s_setprio(0);
    }
    if (kt < 7) stage_half(kt + 1, nA, nB, 1);  // 4 loads -> 8 outstanding
    // ---- sub-phase ks=1 ----
    {
      bf16x8 af[4], bfr[4];
#pragma unroll
      for (int mi = 0; mi < 4; ++mi) af[mi] = *(const bf16x8*)(curA + offA[1][mi]);
#pragma unroll
      for (int ni = 0; ni < 4; ++ni) bfr[ni] = *(const bf16x8*)(curB + offB[1][ni]);
      asm volatile("s_waitcnt lgkmcnt(0)" ::: "memory");
      __builtin_amdgcn_sched_barrier(0);
      __builtin_amdgcn_s_setprio(1);
#pragma unroll
      for (int mi = 0; mi < 4; ++mi)
#pragma unroll
        for (int ni = 0; ni < 4; ++ni)
          acc[mi][ni] = __builtin_amdgcn_mfma_f32_16x16x32_bf16(af[mi], bfr[ni], acc[mi][ni], 0, 0, 0);
      __builtin_amdgcn_s_setprio(0);
    }
    __builtin_amdgcn_s_barrier();          // B: all done reading cur; safe to overwrite
  }

  // epilogue: two row-halves through LDS, then fused LSTM elementwise
#pragma unroll
  for (int half = 0; half < 2; ++half) {
    if (wr == half) {
#pragma unroll
      for (int ni = 0; ni < 4; ++ni) {
        int col = wc * 64 + ni * 16 + l15;
        float bv = bias[n0 + col];
#pragma unroll
        for (int mi = 0; mi < 4; ++mi)
#pragma unroll
          for (int r = 0; r < 4; ++r)
            ldsF[(mi * 16 + l4 * 4 + r) * 132 + col] = acc[mi][ni][r] + bv;
      }
    }
    __syncthreads();
#pragma unroll
    for (int k = 0; k < 8; ++k) {
      int p = tid + k * 256;
      int rl = p >> 5, f = p & 31;
      int n = m0 + half * 64 + rl;
      if (n < N_NODES) {
        float4 pre = *(const float4*)&ldsF[rl * 132 + f * 4];
        int dg = (n0 >> 2) + f;
        float ig = __builtin_amdgcn_rcpf(1.f + __expf(-pre.x));
        float fg = __builtin_amdgcn_rcpf(1.f + __expf(-pre.y));
        float ec = __expf(-2.f * fabsf(pre.z));
        float tg = __builtin_copysignf((1.f - ec) * __builtin_amdgcn_rcpf(1.f + ec), pre.z);
        float og = __builtin_amdgcn_rcpf(1.f + __expf(-pre.w));
        float cOld = cpre[half * 8 + k];
        float cn = fg * cOld + ig * tg;
        float en = __expf(-2.f * fabsf(cn));
        float th = __builtin_copysignf((1.f - en) * __builtin_amdgcn_rcpf(1.f + en), cn);
        out[(size_t)n * 128 + dg] = og * th;
      }
    }
    __syncthreads();
  }
}

extern "C" void kernel_launch(void* const* d_in, const int* in_sizes, int n_in,
                              void* d_out, int out_size, void* d_ws, size_t ws_size,
                              hipStream_t stream) {
  const float* X  = (const float*)d_in[0];
  const int*   ei = (const int*)d_in[1];
  const float* ew = (const float*)d_in[2];
  const float* H  = (const float*)d_in[3];
  const float* C  = (const float*)d_in[4];
  const float* W  = (const float*)d_in[5];
  const float* b  = (const float*)d_in[6];
  const float* cW = (const float*)d_in[7];
  const float* cb = (const float*)d_in[8];
  float* out = (float*)d_out;
  char* ws = (char*)d_ws;

  float*    deg  = (float*)(ws);                 // 0.5 MB
  int*      cnt  = (int*)(ws + 0x80000);         // 0.5 MB
  int2*     bE   = (int2*)(ws + 0x100000);       // 51.2 MB CAP buckets (row, s)
  float*    T1   = (float*)(ws + 0x3500000);     // 51.2 MB
  ushort_t* U    = (ushort_t*)(ws + 0x6600000);  // 100096 x 512 bf16 = 102.5 MB
  ushort_t* Bt   = (ushort_t*)(ws + 0xC800000);  // 512 KB
  float*    bias = (float*)(ws + 0xC880000);     // 2 KB

  hipMemsetAsync(ws, 0, 0x100000, stream);       // zero deg + cnt

  k_misc<<<19774, 256, 0, stream>>>(ei, ew, X, H, deg, U, W, b, cW, cb, Bt, bias);
  k_bucket<<<(N_EDGES + 255) / 256, 256, 0, stream>>>(ei, ew, deg, cnt, bE);
  k_gather<1><<<(N_NODES + 15) / 16, 512, 0, stream>>>(cnt, bE, deg, H, nullptr, T1, U);
  k_gather<2><<<(N_NODES + 15) / 16, 512, 0, stream>>>(cnt, bE, deg, T1, H, nullptr, U);
  k_gemm<<<3128, 256, 0, stream>>>(U, Bt, bias, C, out);
}

// Round 8
// 464.837 us; speedup vs baseline: 1.2903x; 1.1636x over previous
//
#include <hip/hip_runtime.h>

#define N_NODES 100000
#define N_EDGES 1600000
#define CAP 64

typedef unsigned short ushort_t;
typedef __attribute__((ext_vector_type(8))) short bf16x8;
typedef __attribute__((ext_vector_type(4))) float f32x4;
typedef __attribute__((ext_vector_type(4))) int int4e;
typedef __attribute__((ext_vector_type(4))) unsigned short ushort4e;

__device__ __forceinline__ unsigned short f2bf(float f) {
  unsigned int u = __float_as_uint(f);
  u = (u + 0x7FFFu + ((u >> 16) & 1u)) >> 16;
  return (unsigned short)u;
}

// ---- fused: deg atomics (blocks 0-6249) | pack X,H->U bf16 (6250-18749) | B^T+bias (18750-19773) ----
__global__ __launch_bounds__(256) void k_misc(
    const int* __restrict__ ei, const float* __restrict__ ew,
    const float* __restrict__ X, const float* __restrict__ H,
    float* __restrict__ deg, ushort_t* __restrict__ U,
    const float* __restrict__ W, const float* __restrict__ b,
    const float* __restrict__ cW, const float* __restrict__ cb,
    ushort_t* __restrict__ Bt, float* __restrict__ bias) {
  int bid = blockIdx.x;
  if (bid < 6250) {                       // deg[row] += ew  (atomic-latency-bound)
    int e = bid * 256 + threadIdx.x;
    atomicAdd(&deg[ei[e]], ew[e]);
  } else if (bid < 18750) {               // pack X (cols 0-127), H (cols 128-255)
    int i = (bid - 6250) * 256 + threadIdx.x;
    int n = i >> 5, q = i & 31;
    float4 x = *(const float4*)(X + (size_t)n * 128 + q * 4);
    float4 h = *(const float4*)(H + (size_t)n * 128 + q * 4);
    ushort4 a, bb;
    a.x = f2bf(x.x); a.y = f2bf(x.y); a.z = f2bf(x.z); a.w = f2bf(x.w);
    bb.x = f2bf(h.x); bb.y = f2bf(h.y); bb.z = f2bf(h.z); bb.w = f2bf(h.w);
    *(ushort4*)(U + (size_t)n * 512 + q * 4) = a;
    *(ushort4*)(U + (size_t)n * 512 + 128 + q * 4) = bb;
  } else {                                // B^T [512 j][512 k], j = d*4+g; bias
    int idx = (bid - 18750) * 256 + threadIdx.x;
    int j = idx >> 9, k = idx & 511;
    int dd = j >> 2, g = j & 3;
    float v;
    if (k < 128) v = W[(g * 128 + k) * 128 + dd];
    else {
      int kk = k - 128;
      int blk = kk >> 7;
      v = cW[((g * 3 + blk) * 128 + (kk & 127)) * 128 + dd];
    }
    Bt[idx] = f2bf(v);
    if (k == 0) bias[j] = b[g * 128 + dd] + cb[g * 128 + dd];
  }
}

// ---- bucket edges by dst, storing (row, rsqrt(deg[row])*ew); dinv[c] applied in gather ----
__global__ void k_bucket(const int* __restrict__ ei, const float* __restrict__ ew,
                         const float* __restrict__ deg, int* __restrict__ cnt,
                         int2* __restrict__ bE) {
  int e = blockIdx.x * 256 + threadIdx.x;
  if (e >= N_EDGES) return;
  int r = ei[e], c = ei[N_EDGES + e];
  float dr = deg[r];
  float s = dr > 0.f ? rsqrtf(dr) * ew[e] : 0.f;
  int pos = atomicAdd(&cnt[c], 1);
  if (pos < CAP) bE[c * CAP + pos] = make_int2(r, __float_as_int(s));
}

#define FMA4(A, W, V) \
  A.x = fmaf(W, V.x, A.x); A.y = fmaf(W, V.y, A.y); \
  A.z = fmaf(W, V.z, A.z); A.w = fmaf(W, V.w, A.w);

// load 4 bf16 (8B) from U row `p`, convert to f32
#define GATH(vv, p) { \
  ushort4 rw = *(const ushort4*)(sb + (size_t)(p) * 512); \
  vv.x = __uint_as_float((unsigned)rw.x << 16); \
  vv.y = __uint_as_float((unsigned)rw.y << 16); \
  vv.z = __uint_as_float((unsigned)rw.z << 16); \
  vv.w = __uint_as_float((unsigned)rw.w << 16); }

// ---- bf16-source gather: 32 lanes/node, 8 nodes/block (256 thr), 8-deep ILP ----
// PHASE 1: T1 = L_hat @ bf16(H)   (src U+128) -> U cols 256..383
// PHASE 2: T2 = 2*L_hat @ bf16(T1) - H (src U+256) -> U cols 384..511
template <int PHASE>
__global__ __launch_bounds__(256) void k_gather(
    const int* __restrict__ cnt, const int2* __restrict__ bE,
    const float* __restrict__ deg, const float* __restrict__ H,
    ushort_t* __restrict__ U) {
  int g = threadIdx.x >> 5, lane = threadIdx.x & 31;
  int node = blockIdx.x * 8 + g;
  if (node >= N_NODES) return;
  int cn = cnt[node]; if (cn > CAP) cn = CAP;
  const int2* be = bE + node * CAP;
  const ushort_t* sb = U + (PHASE == 1 ? 128 : 256) + lane * 4;
  float dc = deg[node];
  float sc = dc > 0.f ? -rsqrtf(dc) : 0.f;   // -dinv[c], factored out of the sum

  float4 z = {0.f, 0.f, 0.f, 0.f};
  float4 a0 = z, a1 = z, a2 = z, a3 = z, a4 = z, a5 = z, a6 = z, a7 = z;
  int i = 0;
  for (; i + 8 <= cn; i += 8) {
    int4e p0 = __builtin_nontemporal_load((const int4e*)(be + i));
    int4e p1 = __builtin_nontemporal_load((const int4e*)(be + i + 2));
    int4e p2 = __builtin_nontemporal_load((const int4e*)(be + i + 4));
    int4e p3 = __builtin_nontemporal_load((const int4e*)(be + i + 6));
    float4 v0, v1, v2, v3, v4, v5, v6, v7;
    GATH(v0, p0.x); GATH(v1, p0.z); GATH(v2, p1.x); GATH(v3, p1.z);
    GATH(v4, p2.x); GATH(v5, p2.z); GATH(v6, p3.x); GATH(v7, p3.z);
    FMA4(a0, __int_as_float(p0.y), v0); FMA4(a1, __int_as_float(p0.w), v1);
    FMA4(a2, __int_as_float(p1.y), v2); FMA4(a3, __int_as_float(p1.w), v3);
    FMA4(a4, __int_as_float(p2.y), v4); FMA4(a5, __int_as_float(p2.w), v5);
    FMA4(a6, __int_as_float(p3.y), v6); FMA4(a7, __int_as_float(p3.w), v7);
  }
  for (; i + 4 <= cn; i += 4) {
    int4e p0 = __builtin_nontemporal_load((const int4e*)(be + i));
    int4e p1 = __builtin_nontemporal_load((const int4e*)(be + i + 2));
    float4 v0, v1, v2, v3;
    GATH(v0, p0.x); GATH(v1, p0.z); GATH(v2, p1.x); GATH(v3, p1.z);
    FMA4(a0, __int_as_float(p0.y), v0); FMA4(a1, __int_as_float(p0.w), v1);
    FMA4(a2, __int_as_float(p1.y), v2); FMA4(a3, __int_as_float(p1.w), v3);
  }
  for (; i < cn; ++i) {
    int2 p = be[i];
    float4 v;
    GATH(v, p.x);
    FMA4(a0, __int_as_float(p.y), v);
  }
  float4 acc;
  acc.x = sc * (((a0.x + a1.x) + (a2.x + a3.x)) + ((a4.x + a5.x) + (a6.x + a7.x)));
  acc.y = sc * (((a0.y + a1.y) + (a2.y + a3.y)) + ((a4.y + a5.y) + (a6.y + a7.y)));
  acc.z = sc * (((a0.z + a1.z) + (a2.z + a3.z)) + ((a4.z + a5.z) + (a6.z + a7.z)));
  acc.w = sc * (((a0.w + a1.w) + (a2.w + a3.w)) + ((a4.w + a5.w) + (a6.w + a7.w)));

  if (PHASE == 1) {
    ushort4e u = {f2bf(acc.x), f2bf(acc.y), f2bf(acc.z), f2bf(acc.w)};
    __builtin_nontemporal_store(u, (ushort4e*)(U + (size_t)node * 512 + 256 + lane * 4));
  } else {
    float4 h = *(const float4*)(H + (size_t)node * 128 + lane * 4);
    ushort4e u = {f2bf(2.f * acc.x - h.x), f2bf(2.f * acc.y - h.y),
                  f2bf(2.f * acc.z - h.z), f2bf(2.f * acc.w - h.w)};
    __builtin_nontemporal_store(u, (ushort4e*)(U + (size_t)node * 512 + 384 + lane * 4));
  }
}

// ---- fused GEMM, counted-vmcnt depth-2 pipeline + per-ks interleave + setprio ----
__global__ __launch_bounds__(256) void k_gemm(
    const ushort_t* __restrict__ U, const ushort_t* __restrict__ Bt,
    const float* __restrict__ bias, const float* __restrict__ C,
    float* __restrict__ out) {
  __shared__ char ldsRaw[65536];     // 2 x (16K A + 16K B); epilogue reuses as f32 tile
  char* ldsA0 = ldsRaw;
  char* ldsB0 = ldsRaw + 16384;
  char* ldsA1 = ldsRaw + 32768;
  char* ldsB1 = ldsRaw + 49152;
  float* ldsF = (float*)ldsRaw;

  const int tid = threadIdx.x;
  const int lane = tid & 63;
  const int w = tid >> 6;
  const int wr = w >> 1, wc = w & 1;
  // XCD-bijective swizzle: 3128 = 8*391; 4 n-tiles of an m-panel stay in one XCD
  const int b = blockIdx.x;
  const int g = (b & 7) * 391 + (b >> 3);
  const int m0 = (g >> 2) * 128;
  const int n0 = (g & 3) * 128;
  const int l15 = lane & 15;
  const int l4 = lane >> 4;

  auto stage_half = [&](int kt, char* la_base, char* lb_base, int h) {
    const int k0 = kt * 64;
#pragma unroll
    for (int is = 2 * h; is < 2 * h + 2; ++is) {
      int s = is * 256 + tid;
      int row = s >> 3;
      int cs = (s & 7) ^ (row & 7);        // inverse-swizzled global source chunk
      const ushort_t* ga = U + (size_t)(m0 + row) * 512 + k0 + cs * 8;
      const ushort_t* gb = Bt + (size_t)(n0 + row) * 512 + k0 + cs * 8;
      char* la = la_base + (is * 256 + (tid & 192)) * 16;   // wave-uniform base
      char* lb = lb_base + (is * 256 + (tid & 192)) * 16;
      __builtin_amdgcn_global_load_lds((const __attribute__((address_space(1))) void*)ga,
                                       (__attribute__((address_space(3))) void*)la, 16, 0, 0);
      __builtin_amdgcn_global_load_lds((const __attribute__((address_space(1))) void*)gb,
                                       (__attribute__((address_space(3))) void*)lb, 16, 0, 0);
    }
  };

  // C prefetch (epilogue operand), coalesced, issued before staging
  const int fcol = tid & 31;
  const int rbase = tid >> 5;
  float cpre[16];
#pragma unroll
  for (int half = 0; half < 2; ++half)
#pragma unroll
    for (int k = 0; k < 8; ++k) {
      int n = m0 + half * 64 + rbase + k * 8;
      int dg = (n0 >> 2) + fcol;
      cpre[half * 8 + k] = (n < N_NODES) ? C[(size_t)n * 128 + dg] : 0.f;
    }

  // loop-invariant swizzled LDS read offsets (slot independent of mi: 16%8==0)
  int offA[2][4], offB[2][4];
#pragma unroll
  for (int ks = 0; ks < 2; ++ks) {
    int slot = ((ks * 4 + l4) ^ (l15 & 7)) * 16;
#pragma unroll
    for (int i = 0; i < 4; ++i) {
      offA[ks][i] = (wr * 64 + i * 16 + l15) * 128 + slot;
      offB[ks][i] = (wc * 64 + i * 16 + l15) * 128 + slot;
    }
  }

  f32x4 acc[4][4] = {};

  stage_half(0, ldsA0, ldsB0, 0);
  stage_half(0, ldsA0, ldsB0, 1);          // 8 loads outstanding

  for (int kt = 0; kt < 8; ++kt) {
    char* curA = (kt & 1) ? ldsA1 : ldsA0;
    char* curB = (kt & 1) ? ldsB1 : ldsB0;
    char* nA = (kt & 1) ? ldsA0 : ldsA1;
    char* nB = (kt & 1) ? ldsB0 : ldsB1;
    if (kt < 7) {
      stage_half(kt + 1, nA, nB, 0);       // 4 loads -> 12 outstanding
      asm volatile("s_waitcnt vmcnt(4)" ::: "memory");  // stage(kt) landed; half1 in flight
    } else {
      asm volatile("s_waitcnt vmcnt(0)" ::: "memory");
    }
    __builtin_amdgcn_s_barrier();          // A: cur fully staged for all threads
    __builtin_amdgcn_sched_barrier(0);

    // ---- sub-phase ks=0 ----
    {
      bf16x8 af[4], bfr[4];
#pragma unroll
      for (int mi = 0; mi < 4; ++mi) af[mi] = *(const bf16x8*)(curA + offA[0][mi]);
#pragma unroll
      for (int ni = 0; ni < 4; ++ni) bfr[ni] = *(const bf16x8*)(curB + offB[0][ni]);
      asm volatile("s_waitcnt lgkmcnt(0)" ::: "memory");
      __builtin_amdgcn_sched_barrier(0);
      __builtin_amdgcn_s_setprio(1);
#pragma unroll
      for (int mi = 0; mi < 4; ++mi)
#pragma unroll
        for (int ni = 0; ni < 4; ++ni)
          acc[mi][ni] = __builtin_amdgcn_mfma_f32_16x16x32_bf16(af[mi], bfr[ni], acc[mi][ni], 0, 0, 0);
      __builtin_amdgcn_s_setprio(0);
    }
    if (kt < 7) stage_half(kt + 1, nA, nB, 1);  // 4 loads -> 8 outstanding
    // ---- sub-phase ks=1 ----
    {
      bf16x8 af[4], bfr[4];
#pragma unroll
      for (int mi = 0; mi < 4; ++mi) af[mi] = *(const bf16x8*)(curA + offA[1][mi]);
#pragma unroll
      for (int ni = 0; ni < 4; ++ni) bfr[ni] = *(const bf16x8*)(curB + offB[1][ni]);
      asm volatile("s_waitcnt lgkmcnt(0)" ::: "memory");
      __builtin_amdgcn_sched_barrier(0);
      __builtin_amdgcn_s_setprio(1);
#pragma unroll
      for (int mi = 0; mi < 4; ++mi)
#pragma unroll
        for (int ni = 0; ni < 4; ++ni)
          acc[mi][ni] = __builtin_amdgcn_mfma_f32_16x16x32_bf16(af[mi], bfr[ni], acc[mi][ni], 0, 0, 0);
      __builtin_amdgcn_s_setprio(0);
    }
    __builtin_amdgcn_s_barrier();          // B: all done reading cur; safe to overwrite
  }

  // epilogue: two row-halves through LDS, then fused LSTM elementwise
#pragma unroll
  for (int half = 0; half < 2; ++half) {
    if (wr == half) {
#pragma unroll
      for (int ni = 0; ni < 4; ++ni) {
        int col = wc * 64 + ni * 16 + l15;
        float bv = bias[n0 + col];
#pragma unroll
        for (int mi = 0; mi < 4; ++mi)
#pragma unroll
          for (int r = 0; r < 4; ++r)
            ldsF[(mi * 16 + l4 * 4 + r) * 132 + col] = acc[mi][ni][r] + bv;
      }
    }
    __syncthreads();
#pragma unroll
    for (int k = 0; k < 8; ++k) {
      int p = tid + k * 256;
      int rl = p >> 5, f = p & 31;
      int n = m0 + half * 64 + rl;
      if (n < N_NODES) {
        float4 pre = *(const float4*)&ldsF[rl * 132 + f * 4];
        int dg = (n0 >> 2) + f;
        float ig = __builtin_amdgcn_rcpf(1.f + __expf(-pre.x));
        float fg = __builtin_amdgcn_rcpf(1.f + __expf(-pre.y));
        float ec = __expf(-2.f * fabsf(pre.z));
        float tg = __builtin_copysignf((1.f - ec) * __builtin_amdgcn_rcpf(1.f + ec), pre.z);
        float og = __builtin_amdgcn_rcpf(1.f + __expf(-pre.w));
        float cOld = cpre[half * 8 + k];
        float cn = fg * cOld + ig * tg;
        float en = __expf(-2.f * fabsf(cn));
        float th = __builtin_copysignf((1.f - en) * __builtin_amdgcn_rcpf(1.f + en), cn);
        out[(size_t)n * 128 + dg] = og * th;
      }
    }
    __syncthreads();
  }
}

extern "C" void kernel_launch(void* const* d_in, const int* in_sizes, int n_in,
                              void* d_out, int out_size, void* d_ws, size_t ws_size,
                              hipStream_t stream) {
  const float* X  = (const float*)d_in[0];
  const int*   ei = (const int*)d_in[1];
  const float* ew = (const float*)d_in[2];
  const float* H  = (const float*)d_in[3];
  const float* C  = (const float*)d_in[4];
  const float* W  = (const float*)d_in[5];
  const float* b  = (const float*)d_in[6];
  const float* cW = (const float*)d_in[7];
  const float* cb = (const float*)d_in[8];
  float* out = (float*)d_out;
  char* ws = (char*)d_ws;

  float*    deg  = (float*)(ws);                 // 0.5 MB
  int*      cnt  = (int*)(ws + 0x80000);         // 0.5 MB
  int2*     bE   = (int2*)(ws + 0x100000);       // 51.2 MB CAP buckets (row, s)
  ushort_t* U    = (ushort_t*)(ws + 0x3500000);  // 100096 x 512 bf16 = 102.5 MB
  ushort_t* Bt   = (ushort_t*)(ws + 0x9700000);  // 512 KB
  float*    bias = (float*)(ws + 0x9780000);     // 2 KB

  hipMemsetAsync(ws, 0, 0x100000, stream);       // zero deg + cnt

  k_misc<<<19774, 256, 0, stream>>>(ei, ew, X, H, deg, U, W, b, cW, cb, Bt, bias);
  k_bucket<<<(N_EDGES + 255) / 256, 256, 0, stream>>>(ei, ew, deg, cnt, bE);
  k_gather<1><<<(N_NODES + 7) / 8, 256, 0, stream>>>(cnt, bE, deg, H, U);
  k_gather<2><<<(N_NODES + 7) / 8, 256, 0, stream>>>(cnt, bE, deg, H, U);
  k_gemm<<<3128, 256, 0, stream>>>(U, Bt, bias, C, out);
}